// Round 1
// baseline (13219.246 us; speedup 1.0000x reference)
//
#include <hip/hip_runtime.h>

#define TT 16384
#define DD 100
#define HH 50
#define XG_STRIDE 160

// workspace layout (floats)
#define WS_XG 0
#define WS_HS (2 * TT * XG_STRIDE)
#define WS_EV (WS_HS + 2 * TT * 64)

// output offsets (floats)
#define OFF_MU ((size_t)TT * 64 * 64)          // 67,108,864
#define OFF_J  (OFF_MU + (size_t)TT * 64)      // 68,157,440
#define OFF_H  (OFF_J + (size_t)TT * 64 * 64)  // 135,266,304

// ---------------------------------------------------------------------------
// Kernel 1: xi = y @ Wi for both directions (bwd uses flipped y), then apply
// the time-independent x-side LayerNorms (rows 0,2,4 of ls/lb).
// One block per (t, dir). xg[dir][t][0..149] = LN'd gates (r,z,n).
// ---------------------------------------------------------------------------
__global__ __launch_bounds__(160) void xprep_kernel(
    const float* __restrict__ y,
    const float* __restrict__ Wi_f, const float* __restrict__ Wi_b,
    const float* __restrict__ ls_f, const float* __restrict__ lb_f,
    const float* __restrict__ ls_b, const float* __restrict__ lb_b,
    float* __restrict__ xg)
{
    const int t = blockIdx.x;
    const int dir = blockIdx.y;
    const float* __restrict__ Wi = dir ? Wi_b : Wi_f;
    const float* __restrict__ ls = dir ? ls_b : ls_f;
    const float* __restrict__ lb = dir ? lb_b : lb_f;
    const int row = dir ? (TT - 1 - t) : t;

    __shared__ float ys[DD];
    __shared__ float xs[152];
    const int tid = threadIdx.x;
    if (tid < DD) ys[tid] = y[(size_t)row * DD + tid];
    __syncthreads();

    float acc = 0.f;
    if (tid < 150) {
        #pragma unroll 4
        for (int k = 0; k < DD; ++k) acc = fmaf(ys[k], Wi[k * 150 + tid], acc);
        xs[tid] = acc;
    }
    __syncthreads();

    if (tid < 150) {
        const int g = tid / 50, i = tid - g * 50;
        float s = 0.f, s2 = 0.f;
        for (int k = 0; k < 50; ++k) {
            const float v = xs[g * 50 + k];
            s += v;
            s2 = fmaf(v, v, s2);
        }
        const float mean = s * 0.02f;
        const float var  = s2 * 0.02f - mean * mean;
        const float rstd = rsqrtf(var + 1e-6f);
        const int lrow = 2 * g * 50 + i;  // ls rows 0,2,4
        xg[((size_t)dir * TT + t) * XG_STRIDE + tid] =
            (acc - mean) * rstd * ls[lrow] + lb[lrow];
    }
}

// ---------------------------------------------------------------------------
// Kernel 2: the sequential GRU scan. One wave (64 lanes) per direction.
// Lane i (< 50) owns output unit i of all three gates; Wh columns live in
// VGPRs; h is broadcast through a 52-float LDS buffer (float4 reads).
// ---------------------------------------------------------------------------
__global__ __launch_bounds__(64, 1) void scan_kernel(
    const float* __restrict__ xg,
    const float* __restrict__ Wh_f, const float* __restrict__ Wh_b,
    const float* __restrict__ ls_f, const float* __restrict__ lb_f,
    const float* __restrict__ ls_b, const float* __restrict__ lb_b,
    float* __restrict__ hs)
{
    const int dir = blockIdx.x;
    const float* __restrict__ Wh = dir ? Wh_b : Wh_f;
    const float* __restrict__ ls = dir ? ls_b : ls_f;
    const float* __restrict__ lb = dir ? lb_b : lb_f;
    const float* __restrict__ xgd = xg + (size_t)dir * TT * XG_STRIDE;
    float* __restrict__ hsd = hs + (size_t)dir * TT * 64;

    const int lane = threadIdx.x;
    const bool act = lane < HH;

    __shared__ __align__(16) float hb[52];
    if (lane < 52) hb[lane] = 0.f;

    float wr[52], wz[52], wn[52];
    #pragma unroll
    for (int k = 0; k < 52; ++k) { wr[k] = 0.f; wz[k] = 0.f; wn[k] = 0.f; }
    float s1 = 0.f, b1 = 0.f, s3 = 0.f, b3 = 0.f, s5 = 0.f, b5 = 0.f;
    if (act) {
        #pragma unroll
        for (int k = 0; k < HH; ++k) {
            wr[k] = Wh[k * 150 + lane];
            wz[k] = Wh[k * 150 + 50 + lane];
            wn[k] = Wh[k * 150 + 100 + lane];
        }
        s1 = ls[50 + lane];  b1 = lb[50 + lane];   // row 1 (hr)
        s3 = ls[150 + lane]; b3 = lb[150 + lane];  // row 3 (hz)
        s5 = ls[250 + lane]; b5 = lb[250 + lane];  // row 5 (hn)
    }
    float hreg = 0.f;
    __syncthreads();

    const int xl = act ? lane : 0;
    // 2-deep prefetch of the LN'd x-gates
    float xr = xgd[xl], xz = xgd[50 + xl], xn = xgd[100 + xl];
    float pxr = xgd[XG_STRIDE + xl];
    float pxz = xgd[XG_STRIDE + 50 + xl];
    float pxn = xgd[XG_STRIDE + 100 + xl];

    for (int t = 0; t < TT; ++t) {
        const int tp = (t + 2 < TT) ? (t + 2) : (TT - 1);
        const float* __restrict__ xp = xgd + (size_t)tp * XG_STRIDE;
        const float qxr = xp[xl], qxz = xp[50 + xl], qxn = xp[100 + xl];

        // hh = h @ Wh  (per-lane: 3 dots of length 52, 4 partial chains each)
        float ar0 = 0.f, ar1 = 0.f, ar2 = 0.f, ar3 = 0.f;
        float az0 = 0.f, az1 = 0.f, az2 = 0.f, az3 = 0.f;
        float an0 = 0.f, an1 = 0.f, an2 = 0.f, an3 = 0.f;
        const float4* hb4 = reinterpret_cast<const float4*>(hb);
        #pragma unroll
        for (int q = 0; q < 13; ++q) {
            const float4 hv = hb4[q];
            ar0 = fmaf(hv.x, wr[4 * q + 0], ar0);
            ar1 = fmaf(hv.y, wr[4 * q + 1], ar1);
            ar2 = fmaf(hv.z, wr[4 * q + 2], ar2);
            ar3 = fmaf(hv.w, wr[4 * q + 3], ar3);
            az0 = fmaf(hv.x, wz[4 * q + 0], az0);
            az1 = fmaf(hv.y, wz[4 * q + 1], az1);
            az2 = fmaf(hv.z, wz[4 * q + 2], az2);
            az3 = fmaf(hv.w, wz[4 * q + 3], az3);
            an0 = fmaf(hv.x, wn[4 * q + 0], an0);
            an1 = fmaf(hv.y, wn[4 * q + 1], an1);
            an2 = fmaf(hv.z, wn[4 * q + 2], an2);
            an3 = fmaf(hv.w, wn[4 * q + 3], an3);
        }
        const float ar = (ar0 + ar1) + (ar2 + ar3);
        const float az = (az0 + az1) + (az2 + az3);
        const float an = (an0 + an1) + (an2 + an3);

        // LN stats: butterfly over 64 lanes (lanes >= 50 contribute 0)
        float sr = ar, qr = ar * ar;
        float sz = az, qz = az * az;
        float sn = an, qn = an * an;
        #pragma unroll
        for (int m = 1; m < 64; m <<= 1) {
            sr += __shfl_xor(sr, m, 64); qr += __shfl_xor(qr, m, 64);
            sz += __shfl_xor(sz, m, 64); qz += __shfl_xor(qz, m, 64);
            sn += __shfl_xor(sn, m, 64); qn += __shfl_xor(qn, m, 64);
        }
        const float i50 = 0.02f;
        const float mr = sr * i50, vr = fmaf(-mr, mr, qr * i50);
        const float mz = sz * i50, vz = fmaf(-mz, mz, qz * i50);
        const float mn = sn * i50, vn = fmaf(-mn, mn, qn * i50);
        const float rr = rsqrtf(vr + 1e-6f);
        const float rz = rsqrtf(vz + 1e-6f);
        const float rn = rsqrtf(vn + 1e-6f);
        const float hrl = (ar - mr) * rr * s1 + b1;
        const float hzl = (az - mz) * rz * s3 + b3;
        const float hnl = (an - mn) * rn * s5 + b5;

        const float r = __builtin_amdgcn_rcpf(1.f + __expf(-(xr + hrl)));
        const float z = __builtin_amdgcn_rcpf(1.f + __expf(-(xz + hzl)));
        const float e2 = __expf(2.f * (xn + r * hnl));
        const float n = 1.f - 2.f * __builtin_amdgcn_rcpf(e2 + 1.f); // tanh
        const float hnew = (1.f - z) * n + z * hreg;

        __syncthreads();  // single-wave: compiles to sched/waitcnt, near-free
        if (act) {
            hb[lane] = hnew;
            hsd[(size_t)t * 64 + lane] = hnew;
        }
        hreg = act ? hnew : 0.f;
        __syncthreads();

        xr = pxr; xz = pxz; xn = pxn;
        pxr = qxr; pxz = qxz; pxn = qxn;
    }
}

// ---------------------------------------------------------------------------
// Kernel 3: out = [h_f(t), h_b(T-1-t)] @ Wd + bd; emit mu, h=mu/ev, stash ev.
// One block (128 threads) per t; thread j owns output column j.
// ---------------------------------------------------------------------------
__global__ __launch_bounds__(128) void out_kernel(
    const float* __restrict__ hs, const float* __restrict__ Wd,
    const float* __restrict__ bd, float* __restrict__ out,
    float* __restrict__ evws)
{
    const int t = blockIdx.x;
    const int j = threadIdx.x;
    __shared__ float cc[DD];
    __shared__ float os[128];
    if (j < 50)
        cc[j] = hs[(size_t)t * 64 + j];
    else if (j < 100)
        cc[j] = hs[(size_t)(TT + (TT - 1 - t)) * 64 + (j - 50)];
    __syncthreads();

    float acc = bd[j];
    #pragma unroll 4
    for (int k = 0; k < DD; ++k) acc = fmaf(cc[k], Wd[k * 128 + j], acc);
    os[j] = acc;
    __syncthreads();

    if (j < 64) {
        const float mu  = os[j];
        const float evv = __expf(os[64 + j]);
        out[OFF_MU + (size_t)t * 64 + j] = mu;
        out[OFF_H  + (size_t)t * 64 + j] = mu / evv;
        evws[(size_t)t * 64 + j] = evv;
    }
}

// ---------------------------------------------------------------------------
// Kernel 4: diagonal fill of Sigma (ev+1e-6) and J (1/ev), zeros elsewhere.
// float4 stores; 545 MB of writes is the floor here.
// ---------------------------------------------------------------------------
__global__ __launch_bounds__(256) void fill_kernel(
    const float* __restrict__ evws, float4* __restrict__ out4)
{
    const long QN = (long)TT * 64 * 16;   // quads per 64x64-diag tensor
    const long JQ = (long)(OFF_J / 4);
    const long stride = (long)gridDim.x * blockDim.x;
    for (long p = (long)blockIdx.x * blockDim.x + threadIdx.x; p < QN; p += stride) {
        const long e = p * 4;
        const int t = (int)(e >> 12);
        const int rem = (int)(e & 4095);
        const int i = rem >> 6;        // row within 64x64
        const int c = rem & 63;        // first col of this quad (mult of 4)
        const float evv = evws[(size_t)t * 64 + i];
        const float sv  = evv + 1e-6f;
        const float jvv = 1.f / evv;
        const int d = i - c;           // diag lands in this quad iff 0<=d<4
        float4 s, jv;
        s.x  = (d == 0) ? sv  : 0.f;  s.y  = (d == 1) ? sv  : 0.f;
        s.z  = (d == 2) ? sv  : 0.f;  s.w  = (d == 3) ? sv  : 0.f;
        jv.x = (d == 0) ? jvv : 0.f;  jv.y = (d == 1) ? jvv : 0.f;
        jv.z = (d == 2) ? jvv : 0.f;  jv.w = (d == 3) ? jvv : 0.f;
        out4[p] = s;
        out4[JQ + p] = jv;
    }
}

// ---------------------------------------------------------------------------
extern "C" void kernel_launch(void* const* d_in, const int* in_sizes, int n_in,
                              void* d_out, int out_size, void* d_ws, size_t ws_size,
                              hipStream_t stream)
{
    const float* y    = (const float*)d_in[0];
    const float* Wi_f = (const float*)d_in[1];
    const float* Wh_f = (const float*)d_in[2];
    const float* ls_f = (const float*)d_in[3];
    const float* lb_f = (const float*)d_in[4];
    const float* Wi_b = (const float*)d_in[5];
    const float* Wh_b = (const float*)d_in[6];
    const float* ls_b = (const float*)d_in[7];
    const float* lb_b = (const float*)d_in[8];
    const float* Wd   = (const float*)d_in[9];
    const float* bd   = (const float*)d_in[10];

    float* out = (float*)d_out;
    float* ws  = (float*)d_ws;
    float* xg  = ws + WS_XG;   // [2][T][160]
    float* hsb = ws + WS_HS;   // [2][T][64]
    float* ev  = ws + WS_EV;   // [T][64]

    xprep_kernel<<<dim3(TT, 2), dim3(160), 0, stream>>>(
        y, Wi_f, Wi_b, ls_f, lb_f, ls_b, lb_b, xg);
    scan_kernel<<<dim3(2), dim3(64), 0, stream>>>(
        xg, Wh_f, Wh_b, ls_f, lb_f, ls_b, lb_b, hsb);
    out_kernel<<<dim3(TT), dim3(128), 0, stream>>>(
        hsb, Wd, bd, out, ev);
    fill_kernel<<<dim3(2048), dim3(256), 0, stream>>>(
        ev, (float4*)out);
}

// Round 3
// 9854.785 us; speedup vs baseline: 1.3414x; 1.3414x over previous
//
#include <hip/hip_runtime.h>

#define TT 16384
#define DD 100
#define HH 50
#define XG_STRIDE 160

// workspace layout (floats)
#define WS_XG 0
#define WS_HS (2 * TT * XG_STRIDE)
#define WS_EV (WS_HS + 2 * TT * 64)

// output offsets (floats)
#define OFF_MU ((size_t)TT * 64 * 64)          // 67,108,864
#define OFF_J  (OFF_MU + (size_t)TT * 64)      // 68,157,440
#define OFF_H  (OFF_J + (size_t)TT * 64 * 64)  // 135,266,304

typedef float v2f __attribute__((ext_vector_type(2)));

// ---------------------------------------------------------------------------
// DPP wave-wide sum: result lands in lane 63. VALU-latency only (no LDS).
// ---------------------------------------------------------------------------
template <int CTRL>
__device__ __forceinline__ float dpp_add(float x) {
    const int y = __builtin_amdgcn_update_dpp(
        0, __builtin_bit_cast(int, x), CTRL, 0xf, 0xf, false);
    return x + __builtin_bit_cast(float, y);
}
__device__ __forceinline__ float wave_sum63(float x) {
    x = dpp_add<0x111>(x);  // row_shr:1
    x = dpp_add<0x112>(x);  // row_shr:2
    x = dpp_add<0x114>(x);  // row_shr:4
    x = dpp_add<0x118>(x);  // row_shr:8  -> lane 15 of each row has row sum
    x = dpp_add<0x142>(x);  // row_bcast:15
    x = dpp_add<0x143>(x);  // row_bcast:31 -> lane 63 has total
    return x;
}
__device__ __forceinline__ float bcast_lane(float x, int l) {
    return __builtin_bit_cast(float,
        __builtin_amdgcn_readlane(__builtin_bit_cast(int, x), l));
}
// Fold the wave-sum * 0.02 (column mean over the 50 real lanes) into lane L
// of the weight register; all other lanes keep their weight. (Init-time only.)
__device__ __forceinline__ float fold_mean(float w, int L, int lane) {
    const float s = wave_sum63(w);
    const float cm = bcast_lane(s, 63) * 0.02f;
    return (lane == L) ? cm : w;
}

// ---------------------------------------------------------------------------
// Kernel 1: xi = y @ Wi for both directions (bwd uses flipped y), then apply
// the time-independent x-side LayerNorms (rows 0,2,4 of ls/lb).
// ---------------------------------------------------------------------------
__global__ __launch_bounds__(160) void xprep_kernel(
    const float* __restrict__ y,
    const float* __restrict__ Wi_f, const float* __restrict__ Wi_b,
    const float* __restrict__ ls_f, const float* __restrict__ lb_f,
    const float* __restrict__ ls_b, const float* __restrict__ lb_b,
    float* __restrict__ xg)
{
    const int t = blockIdx.x;
    const int dir = blockIdx.y;
    const float* __restrict__ Wi = dir ? Wi_b : Wi_f;
    const float* __restrict__ ls = dir ? ls_b : ls_f;
    const float* __restrict__ lb = dir ? lb_b : lb_f;
    const int row = dir ? (TT - 1 - t) : t;

    __shared__ float ys[DD];
    __shared__ float xs[152];
    const int tid = threadIdx.x;
    if (tid < DD) ys[tid] = y[(size_t)row * DD + tid];
    __syncthreads();

    float acc = 0.f;
    if (tid < 150) {
        #pragma unroll 4
        for (int k = 0; k < DD; ++k) acc = fmaf(ys[k], Wi[k * 150 + tid], acc);
        xs[tid] = acc;
    }
    __syncthreads();

    if (tid < 150) {
        const int g = tid / 50, i = tid - g * 50;
        float s = 0.f, s2 = 0.f;
        for (int k = 0; k < 50; ++k) {
            const float v = xs[g * 50 + k];
            s += v;
            s2 = fmaf(v, v, s2);
        }
        const float mean = s * 0.02f;
        const float var  = s2 * 0.02f - mean * mean;
        const float rstd = rsqrtf(var + 1e-6f);
        const int lrow = 2 * g * 50 + i;  // ls rows 0,2,4
        xg[((size_t)dir * TT + t) * XG_STRIDE + tid] =
            (acc - mean) * rstd * ls[lrow] + lb[lrow];
    }
}

// ---------------------------------------------------------------------------
// Kernel 2: sequential GRU scan. One wave per direction, no barriers
// (single-wave DS ops are in-order). DPP reductions, v_pk_fma_f32 matvec,
// means computed via precomputed column-mean columns in lanes 50/51/52.
// ---------------------------------------------------------------------------
__global__ __launch_bounds__(64, 1) void scan_kernel(
    const float* __restrict__ xg,
    const float* __restrict__ Wh_f, const float* __restrict__ Wh_b,
    const float* __restrict__ ls_f, const float* __restrict__ lb_f,
    const float* __restrict__ ls_b, const float* __restrict__ lb_b,
    float* __restrict__ hs)
{
    const int dir = blockIdx.x;
    const float* __restrict__ Wh = dir ? Wh_b : Wh_f;
    const float* __restrict__ ls = dir ? ls_b : ls_f;
    const float* __restrict__ lb = dir ? lb_b : lb_f;
    const float* __restrict__ xgd = xg + (size_t)dir * TT * XG_STRIDE;
    float* __restrict__ hsd = hs + (size_t)dir * TT * 64;

    const int lane = threadIdx.x;
    const bool act = lane < HH;

    __shared__ __align__(16) float hb[52];
    if (lane < 52) hb[lane] = 0.f;

    // Wh columns in VGPRs as packed pairs over the h index (k = 2p, 2p+1)
    v2f wr2[26], wz2[26], wn2[26];
    #pragma unroll
    for (int p = 0; p < 26; ++p) {
        wr2[p] = (v2f){0.f, 0.f};
        wz2[p] = (v2f){0.f, 0.f};
        wn2[p] = (v2f){0.f, 0.f};
    }
    float s1 = 0.f, b1 = 0.f, s3 = 0.f, b3 = 0.f, s5 = 0.f, b5 = 0.f;
    if (act) {
        #pragma unroll
        for (int k = 0; k < HH; ++k) {
            const float a = Wh[k * 150 + lane];
            const float b = Wh[k * 150 + 50 + lane];
            const float c = Wh[k * 150 + 100 + lane];
            if (k & 1) { wr2[k >> 1].y = a; wz2[k >> 1].y = b; wn2[k >> 1].y = c; }
            else       { wr2[k >> 1].x = a; wz2[k >> 1].x = b; wn2[k >> 1].x = c; }
        }
        s1 = ls[50 + lane];  b1 = lb[50 + lane];   // row 1 (hr)
        s3 = ls[150 + lane]; b3 = lb[150 + lane];  // row 3 (hz)
        s5 = ls[250 + lane]; b5 = lb[250 + lane];  // row 5 (hn)
    }
    // Fold column means into lanes 50 (r), 51 (z), 52 (n): after this,
    // lane 50's "ar" = mean(hh_r), etc. (mean is linear in h).
    #pragma unroll
    for (int p = 0; p < 26; ++p) {
        wr2[p].x = fold_mean(wr2[p].x, 50, lane);
        wr2[p].y = fold_mean(wr2[p].y, 50, lane);
        wz2[p].x = fold_mean(wz2[p].x, 51, lane);
        wz2[p].y = fold_mean(wz2[p].y, 51, lane);
        wn2[p].x = fold_mean(wn2[p].x, 52, lane);
        wn2[p].y = fold_mean(wn2[p].y, 52, lane);
    }

    float hreg = 0.f;
    const int xl = act ? lane : 0;
    // 2-deep prefetch of the LN'd x-gates
    float xr = xgd[xl], xz = xgd[50 + xl], xn = xgd[100 + xl];
    float pxr = xgd[XG_STRIDE + xl];
    float pxz = xgd[XG_STRIDE + 50 + xl];
    float pxn = xgd[XG_STRIDE + 100 + xl];

    #pragma unroll 1
    for (int t = 0; t < TT; ++t) {
        const int tp = (t + 2 < TT) ? (t + 2) : (TT - 1);
        const float* __restrict__ xp = xgd + (size_t)tp * XG_STRIDE;
        const float qxr = xp[xl], qxz = xp[50 + xl], qxn = xp[100 + xl];

        // hh = h @ Wh  via packed fp32 FMA (v_pk_fma_f32), 2 chains/gate
        v2f ar0 = {0.f, 0.f}, ar1 = {0.f, 0.f};
        v2f az0 = {0.f, 0.f}, az1 = {0.f, 0.f};
        v2f an0 = {0.f, 0.f}, an1 = {0.f, 0.f};
        const float4* hb4 = reinterpret_cast<const float4*>(hb);
        #pragma unroll
        for (int q = 0; q < 13; ++q) {
            const float4 hv = hb4[q];
            const v2f h0 = {hv.x, hv.y};
            const v2f h1 = {hv.z, hv.w};
            ar0 = __builtin_elementwise_fma(h0, wr2[2 * q],     ar0);
            ar1 = __builtin_elementwise_fma(h1, wr2[2 * q + 1], ar1);
            az0 = __builtin_elementwise_fma(h0, wz2[2 * q],     az0);
            az1 = __builtin_elementwise_fma(h1, wz2[2 * q + 1], az1);
            an0 = __builtin_elementwise_fma(h0, wn2[2 * q],     an0);
            an1 = __builtin_elementwise_fma(h1, wn2[2 * q + 1], an1);
        }
        const float ar = (ar0.x + ar0.y) + (ar1.x + ar1.y);
        const float az = (az0.x + az0.y) + (az1.x + az1.y);
        const float an = (an0.x + an0.y) + (an1.x + an1.y);

        // means came out of the matvec (lanes 50/51/52)
        const float mr = bcast_lane(ar, 50);
        const float mz = bcast_lane(az, 51);
        const float mn = bcast_lane(an, 52);

        // sum of squares over the 50 real lanes (DPP, result lane 63)
        const float qrv = act ? ar * ar : 0.f;
        const float qzv = act ? az * az : 0.f;
        const float qnv = act ? an * an : 0.f;
        const float Sr = bcast_lane(wave_sum63(qrv), 63);
        const float Sz = bcast_lane(wave_sum63(qzv), 63);
        const float Sn = bcast_lane(wave_sum63(qnv), 63);

        const float i50 = 0.02f;
        const float vr = fmaf(-mr, mr, Sr * i50);
        const float vz = fmaf(-mz, mz, Sz * i50);
        const float vn = fmaf(-mn, mn, Sn * i50);
        const float rr = rsqrtf(vr + 1e-6f);
        const float rz = rsqrtf(vz + 1e-6f);
        const float rn = rsqrtf(vn + 1e-6f);
        const float hrl = (ar - mr) * rr * s1 + b1;
        const float hzl = (az - mz) * rz * s3 + b3;
        const float hnl = (an - mn) * rn * s5 + b5;

        const float r = __builtin_amdgcn_rcpf(1.f + __expf(-(xr + hrl)));
        const float z = __builtin_amdgcn_rcpf(1.f + __expf(-(xz + hzl)));
        const float e2 = __expf(2.f * (xn + r * hnl));
        const float n = 1.f - 2.f * __builtin_amdgcn_rcpf(e2 + 1.f); // tanh
        const float hnew = (1.f - z) * n + z * hreg;

        // single wave: same-wave LDS ops are in-order, no barrier needed
        if (act) {
            hb[lane] = hnew;
            hsd[(size_t)t * 64 + lane] = hnew;
        }
        hreg = act ? hnew : 0.f;

        xr = pxr; xz = pxz; xn = pxn;
        pxr = qxr; pxz = qxz; pxn = qxn;
    }
}

// ---------------------------------------------------------------------------
// Kernel 3: out = [h_f(t), h_b(T-1-t)] @ Wd + bd; emit mu, h=mu/ev, stash ev.
// ---------------------------------------------------------------------------
__global__ __launch_bounds__(128) void out_kernel(
    const float* __restrict__ hs, const float* __restrict__ Wd,
    const float* __restrict__ bd, float* __restrict__ out,
    float* __restrict__ evws)
{
    const int t = blockIdx.x;
    const int j = threadIdx.x;
    __shared__ float cc[DD];
    __shared__ float os[128];
    if (j < 50)
        cc[j] = hs[(size_t)t * 64 + j];
    else if (j < 100)
        cc[j] = hs[(size_t)(TT + (TT - 1 - t)) * 64 + (j - 50)];
    __syncthreads();

    float acc = bd[j];
    #pragma unroll 4
    for (int k = 0; k < DD; ++k) acc = fmaf(cc[k], Wd[k * 128 + j], acc);
    os[j] = acc;
    __syncthreads();

    if (j < 64) {
        const float mu  = os[j];
        const float evv = __expf(os[64 + j]);
        out[OFF_MU + (size_t)t * 64 + j] = mu;
        out[OFF_H  + (size_t)t * 64 + j] = mu / evv;
        evws[(size_t)t * 64 + j] = evv;
    }
}

// ---------------------------------------------------------------------------
// Kernel 4: diagonal fill of Sigma (ev+1e-6) and J (1/ev), zeros elsewhere.
// ---------------------------------------------------------------------------
__global__ __launch_bounds__(256) void fill_kernel(
    const float* __restrict__ evws, float4* __restrict__ out4)
{
    const long QN = (long)TT * 64 * 16;   // quads per 64x64-diag tensor
    const long JQ = (long)(OFF_J / 4);
    const long stride = (long)gridDim.x * blockDim.x;
    for (long p = (long)blockIdx.x * blockDim.x + threadIdx.x; p < QN; p += stride) {
        const long e = p * 4;
        const int t = (int)(e >> 12);
        const int rem = (int)(e & 4095);
        const int i = rem >> 6;        // row within 64x64
        const int c = rem & 63;        // first col of this quad (mult of 4)
        const float evv = evws[(size_t)t * 64 + i];
        const float sv  = evv + 1e-6f;
        const float jvv = 1.f / evv;
        const int d = i - c;           // diag lands in this quad iff 0<=d<4
        float4 s, jv;
        s.x  = (d == 0) ? sv  : 0.f;  s.y  = (d == 1) ? sv  : 0.f;
        s.z  = (d == 2) ? sv  : 0.f;  s.w  = (d == 3) ? sv  : 0.f;
        jv.x = (d == 0) ? jvv : 0.f;  jv.y = (d == 1) ? jvv : 0.f;
        jv.z = (d == 2) ? jvv : 0.f;  jv.w = (d == 3) ? jvv : 0.f;
        out4[p] = s;
        out4[JQ + p] = jv;
    }
}

// ---------------------------------------------------------------------------
extern "C" void kernel_launch(void* const* d_in, const int* in_sizes, int n_in,
                              void* d_out, int out_size, void* d_ws, size_t ws_size,
                              hipStream_t stream)
{
    const float* y    = (const float*)d_in[0];
    const float* Wi_f = (const float*)d_in[1];
    const float* Wh_f = (const float*)d_in[2];
    const float* ls_f = (const float*)d_in[3];
    const float* lb_f = (const float*)d_in[4];
    const float* Wi_b = (const float*)d_in[5];
    const float* Wh_b = (const float*)d_in[6];
    const float* ls_b = (const float*)d_in[7];
    const float* lb_b = (const float*)d_in[8];
    const float* Wd   = (const float*)d_in[9];
    const float* bd   = (const float*)d_in[10];

    float* out = (float*)d_out;
    float* ws  = (float*)d_ws;
    float* xg  = ws + WS_XG;   // [2][T][160]
    float* hsb = ws + WS_HS;   // [2][T][64]
    float* ev  = ws + WS_EV;   // [T][64]

    xprep_kernel<<<dim3(TT, 2), dim3(160), 0, stream>>>(
        y, Wi_f, Wi_b, ls_f, lb_f, ls_b, lb_b, xg);
    scan_kernel<<<dim3(2), dim3(64), 0, stream>>>(
        xg, Wh_f, Wh_b, ls_f, lb_f, ls_b, lb_b, hsb);
    out_kernel<<<dim3(TT), dim3(128), 0, stream>>>(
        hsb, Wd, bd, out, ev);
    fill_kernel<<<dim3(2048), dim3(256), 0, stream>>>(
        ev, (float4*)out);
}